// Round 3
// baseline (364.272 us; speedup 1.0000x reference)
//
#include <hip/hip_runtime.h>

// MultiHeadAttention: B=2, S=2048, D=1024, H=16, DH=64, causal.
// Pipeline: fp32->bf16 convert, weight transposes, 3 proj GEMMs (bf16 MFMA),
// flash attention (bf16 MFMA, fp32 softmax), output GEMM -> fp32.

typedef short bf16x8 __attribute__((ext_vector_type(8)));
typedef float f32x4 __attribute__((ext_vector_type(4)));

__device__ __forceinline__ unsigned short f2bf(float f){
  unsigned int u = __builtin_bit_cast(unsigned int, f);
  u = (u + 0x7fffu + ((u >> 16) & 1u)) >> 16;
  return (unsigned short)u;
}

__device__ __forceinline__ void gld_lds16(const void* src, void* dst){
  __builtin_amdgcn_global_load_lds((const __attribute__((address_space(1))) unsigned int*)src,
                                   (__attribute__((address_space(3))) unsigned int*)dst,
                                   16, 0, 0);
}

// Stage a [rows][2^rowb_lg2 bytes] bf16 tile from global into LDS (linear dest).
// If swz: source is pre-swizzled so that swizzled ds_reads (byte ^ ((row&7)<<4)) see
// logical data (rule: both-sides-or-neither with global_load_lds).
__device__ __forceinline__ void stage_lds(const char* gtile, size_t growb, char* lds,
                                          int tid, int rowb_lg2, int swz, int tilebytes){
  int w = tid >> 6;
  for (int c = 0; c < tilebytes; c += 4096){
    int o = c + tid*16;
    int row = o >> rowb_lg2;
    int colb = o & ((1 << rowb_lg2) - 1);
    if (swz) colb ^= ((row & 7) << 4);
    gld_lds16(gtile + (size_t)row*growb + colb, lds + c + w*1024);
  }
}

// ---------------- fp32 -> bf16 convert (8 elems/thread) ----------------
__global__ __launch_bounds__(256) void convertx(const float* __restrict__ in,
                                                unsigned short* __restrict__ out, int n8){
  int i = blockIdx.x*blockDim.x + threadIdx.x;
  if (i >= n8) return;
  const float4* p = (const float4*)in;
  float4 a = p[2*i], b = p[2*i+1];
  uint4 o;
  o.x = (unsigned int)f2bf(a.x) | ((unsigned int)f2bf(a.y) << 16);
  o.y = (unsigned int)f2bf(a.z) | ((unsigned int)f2bf(a.w) << 16);
  o.z = (unsigned int)f2bf(b.x) | ((unsigned int)f2bf(b.y) << 16);
  o.w = (unsigned int)f2bf(b.z) | ((unsigned int)f2bf(b.w) << 16);
  ((uint4*)out)[i] = o;
}

// ---------------- transpose fp32 [R][C] -> bf16 [C][R], per-matrix z ----------------
__global__ __launch_bounds__(256) void transpose_bf16(const float* __restrict__ in,
                                                      unsigned short* __restrict__ out,
                                                      int R, int C,
                                                      size_t in_mstride, size_t out_mstride){
  __shared__ unsigned short tile[64][66];   // +2 pad: conflict-free transposed reads
  int t = threadIdx.x;
  int r0 = blockIdx.x*64, c0 = blockIdx.y*64;
  const float* inm = in + (size_t)blockIdx.z*in_mstride;
  unsigned short* outm = out + (size_t)blockIdx.z*out_mstride;
  int j = t & 63, i0 = (t >> 6)*16;
  #pragma unroll
  for (int ii = 0; ii < 16; ii++){
    int i = i0 + ii;
    tile[i][j] = f2bf(inm[(size_t)(r0+i)*C + c0 + j]);
  }
  __syncthreads();
  #pragma unroll
  for (int ii = 0; ii < 16; ii++){
    int i = i0 + ii;                       // out-row within tile (c index)
    outm[(size_t)(c0+i)*R + r0 + j] = tile[j][i];
  }
}

// ---------------- GEMM: C[M,N] = A[M,K](bf16 rm) * BT[N,K](bf16 rm) + bias ----------------
// m97 structure: 128x128 tile, BK=32, 4 waves (2x2 of 64x64), global_load_lds w16, dbuf LDS.
// EPI=0: bf16 out, per-head layout ((m>>11)*16 + (n>>6))*2048*64 + (m&2047)*64 + (n&63), *scale
// EPI=1: fp32 out row-major [M][N]
template<int EPI>
__global__ __launch_bounds__(256) void gemm_bt(const unsigned short* __restrict__ A,
                                               const unsigned short* __restrict__ BT,
                                               const float* __restrict__ bias,
                                               void* __restrict__ outp,
                                               int M, int N, int K, float scale){
  __shared__ __align__(16) unsigned short lA[2][128*32];
  __shared__ __align__(16) unsigned short lB[2][128*32];
  int tid = threadIdx.x, lane = tid & 63, w = tid >> 6;
  int bn = blockIdx.x*128, bm = blockIdx.y*128;
  int wm = (w >> 1)*64, wn = (w & 1)*64;
  int lr = lane & 15;
  int lkb = (lane >> 4)*16;                // byte offset of lane's 8-bf16 k-slice
  const char* Ab = (const char*)(A + (size_t)bm*K);
  const char* Bb = (const char*)(BT + (size_t)bn*K);
  size_t grow = (size_t)K*2;
  int nk = K >> 5;

  f32x4 zf = {0.f,0.f,0.f,0.f};
  f32x4 acc[4][4];
  #pragma unroll
  for (int mi = 0; mi < 4; mi++)
    #pragma unroll
    for (int ni = 0; ni < 4; ni++) acc[mi][ni] = zf;

  stage_lds(Ab, grow, (char*)lA[0], tid, 6, 0, 8192);
  stage_lds(Bb, grow, (char*)lB[0], tid, 6, 0, 8192);
  __syncthreads();
  int cur = 0;
  for (int kt = 0; kt < nk; kt++){
    if (kt + 1 < nk){
      stage_lds(Ab + (size_t)(kt+1)*64, grow, (char*)lA[cur^1], tid, 6, 0, 8192);
      stage_lds(Bb + (size_t)(kt+1)*64, grow, (char*)lB[cur^1], tid, 6, 0, 8192);
    }
    const char* pa = (const char*)lA[cur];
    const char* pb = (const char*)lB[cur];
    bf16x8 af[4], bfr[4];
    #pragma unroll
    for (int mi = 0; mi < 4; mi++)
      af[mi] = *(const bf16x8*)(pa + (wm + mi*16 + lr)*64 + lkb);
    #pragma unroll
    for (int ni = 0; ni < 4; ni++)
      bfr[ni] = *(const bf16x8*)(pb + (wn + ni*16 + lr)*64 + lkb);
    #pragma unroll
    for (int mi = 0; mi < 4; mi++)
      #pragma unroll
      for (int ni = 0; ni < 4; ni++)
        acc[mi][ni] = __builtin_amdgcn_mfma_f32_16x16x32_bf16(af[mi], bfr[ni], acc[mi][ni], 0, 0, 0);
    __syncthreads();
    cur ^= 1;
  }

  #pragma unroll
  for (int mi = 0; mi < 4; mi++)
    #pragma unroll
    for (int ni = 0; ni < 4; ni++)
      #pragma unroll
      for (int r = 0; r < 4; r++){
        int row = bm + wm + mi*16 + (lane >> 4)*4 + r;
        int col = bn + wn + ni*16 + (lane & 15);
        float v = acc[mi][ni][r] + bias[col];
        if (EPI == 0){
          v *= scale;
          unsigned short* o = (unsigned short*)outp;
          o[(size_t)((row >> 11)*16 + (col >> 6))*131072 + (size_t)(row & 2047)*64 + (col & 63)] = f2bf(v);
        } else {
          float* o = (float*)outp;
          o[(size_t)row*N + col] = v;
        }
      }
}

// ---------------- flash attention, causal ----------------
// grid: (S/128, B*H). 4 waves x 32 q-rows. KV tiles of 64. concat out bf16 [B,S,H*DH].
__global__ __launch_bounds__(256) void attn_fwd(const unsigned short* __restrict__ qh,
                                                const unsigned short* __restrict__ kh,
                                                const unsigned short* __restrict__ vh,
                                                unsigned short* __restrict__ cc,
                                                const int* __restrict__ maskp){
  __shared__ __align__(16) unsigned short Qs[128*64];   // 16 KB, swizzled
  __shared__ __align__(16) unsigned short Ks[64*64];    //  8 KB, swizzled
  __shared__ __align__(16) unsigned short VTs[64*64];   //  8 KB, V^T, swizzled
  __shared__ __align__(16) unsigned short Ps[4][32*64]; // 16 KB, per-wave P, swizzled
  int tid = threadIdx.x, lane = tid & 63, w = tid >> 6;
  int lg = lane >> 4, lr = lane & 15;
  int qt = blockIdx.x, bh = blockIdx.y;
  size_t base = (size_t)bh * (2048*64);
  const unsigned short* Q = qh + base;
  const unsigned short* K = kh + base;
  const unsigned short* V = vh + base;
  int q0 = qt*128;
  int causal = *maskp;

  stage_lds((const char*)(Q + (size_t)q0*64), 128, (char*)Qs, tid, 7, 1, 16384);
  __syncthreads();

  bf16x8 qf[2][2];
  #pragma unroll
  for (int mi = 0; mi < 2; mi++)
    #pragma unroll
    for (int kk = 0; kk < 2; kk++){
      int row = w*32 + mi*16 + lr;
      qf[mi][kk] = *(const bf16x8*)((const char*)Qs + row*128 + ((kk*64 + lg*16) ^ ((row & 7) << 4)));
    }

  f32x4 zf = {0.f,0.f,0.f,0.f};
  f32x4 oa[2][4];
  float mr[2][4], lsm[2][4];
  #pragma unroll
  for (int mi = 0; mi < 2; mi++){
    #pragma unroll
    for (int ei = 0; ei < 4; ei++) oa[mi][ei] = zf;
    #pragma unroll
    for (int r = 0; r < 4; r++){ mr[mi][r] = -1e30f; lsm[mi][r] = 0.f; }
  }

  int nt = causal ? (q0/64 + 2) : 32;
  int wq0 = q0 + w*32;

  for (int t = 0; t < nt; t++){
    __syncthreads();   // prev-iter K/V reads done before restage
    stage_lds((const char*)(K + (size_t)t*4096), 128, (char*)Ks, tid, 7, 1, 8192);
    // reg-stage V transposed into VTs (coalesced global read, swizzled 2B LDS writes)
    #pragma unroll
    for (int c = 0; c < 2; c++){
      int o = c*4096 + tid*16;
      uint4 vvv = *(const uint4*)((const char*)V + (size_t)t*8192 + o);
      int kv = o >> 7;
      int e0 = (o & 127) >> 1;
      unsigned int uu[4] = {vvv.x, vvv.y, vvv.z, vvv.w};
      #pragma unroll
      for (int j = 0; j < 4; j++){
        int e1 = e0 + 2*j, e2 = e1 + 1;
        *(unsigned short*)((char*)VTs + e1*128 + ((kv*2) ^ ((e1 & 7) << 4))) = (unsigned short)(uu[j] & 0xffffu);
        *(unsigned short*)((char*)VTs + e2*128 + ((kv*2) ^ ((e2 & 7) << 4))) = (unsigned short)(uu[j] >> 16);
      }
    }
    __syncthreads();   // staging visible to all waves

    if (causal && (t*64 > wq0 + 31)) continue;   // fully-masked for this wave

    // S = Q K^T  (scale already folded into q projection)
    f32x4 sc[2][4];
    #pragma unroll
    for (int mi = 0; mi < 2; mi++)
      #pragma unroll
      for (int ni = 0; ni < 4; ni++) sc[mi][ni] = zf;
    #pragma unroll
    for (int kk = 0; kk < 2; kk++)
      #pragma unroll
      for (int ni = 0; ni < 4; ni++){
        int krow = ni*16 + lr;
        bf16x8 kf = *(const bf16x8*)((const char*)Ks + krow*128 + ((kk*64 + lg*16) ^ ((krow & 7) << 4)));
        #pragma unroll
        for (int mi = 0; mi < 2; mi++)
          sc[mi][ni] = __builtin_amdgcn_mfma_f32_16x16x32_bf16(qf[mi][kk], kf, sc[mi][ni], 0, 0, 0);
      }

    if (causal && (t*64 + 63 > wq0)){
      #pragma unroll
      for (int mi = 0; mi < 2; mi++)
        #pragma unroll
        for (int ni = 0; ni < 4; ni++)
          #pragma unroll
          for (int r = 0; r < 4; r++){
            int qrow = wq0 + mi*16 + lg*4 + r;
            int kvc  = t*64 + ni*16 + lr;
            if (kvc > qrow) sc[mi][ni][r] = -1e9f;
          }
    }

    // online softmax (row owned by the 16 lanes sharing lg; reduce over lane bits 0-3)
    #pragma unroll
    for (int mi = 0; mi < 2; mi++)
      #pragma unroll
      for (int r = 0; r < 4; r++){
        float mx = fmaxf(fmaxf(sc[mi][0][r], sc[mi][1][r]), fmaxf(sc[mi][2][r], sc[mi][3][r]));
        #pragma unroll
        for (int off = 1; off < 16; off <<= 1)
          mx = fmaxf(mx, __shfl_xor(mx, off, 64));
        float mo = mr[mi][r];
        float mn = fmaxf(mo, mx);
        mr[mi][r] = mn;
        float alpha = __expf(mo - mn);
        float psum = 0.f;
        #pragma unroll
        for (int ni = 0; ni < 4; ni++){
          float p = __expf(sc[mi][ni][r] - mn);
          sc[mi][ni][r] = p;
          psum += p;
        }
        #pragma unroll
        for (int off = 1; off < 16; off <<= 1)
          psum += __shfl_xor(psum, off, 64);
        lsm[mi][r] = lsm[mi][r]*alpha + psum;
        // BUGFIX (round 1): rescale ONLY component r of each f32x4 accumulator.
        // Previous code did `oa[mi][ei] *= alpha` which broadcast row-r's alpha
        // onto all 4 rows of the fragment (net effect: alpha0*alpha1*alpha2*alpha3).
        #pragma unroll
        for (int ei = 0; ei < 4; ei++) oa[mi][ei][r] *= alpha;
      }

    // P (bf16) -> per-wave LDS, C-layout write / A-layout read (swizzled rows)
    #pragma unroll
    for (int mi = 0; mi < 2; mi++)
      #pragma unroll
      for (int ni = 0; ni < 4; ni++)
        #pragma unroll
        for (int r = 0; r < 4; r++){
          int prow = mi*16 + lg*4 + r;
          int pcb = (ni*16 + lr)*2;
          *(unsigned short*)((char*)Ps[w] + prow*128 + (pcb ^ ((prow & 7) << 4))) = f2bf(sc[mi][ni][r]);
        }

    // O += P @ V   (DS ops in-order within wave; Ps[w] is wave-private)
    #pragma unroll
    for (int kk = 0; kk < 2; kk++){
      bf16x8 pf[2];
      #pragma unroll
      for (int mi = 0; mi < 2; mi++){
        int prow = mi*16 + lr;
        pf[mi] = *(const bf16x8*)((const char*)Ps[w] + prow*128 + ((kk*64 + lg*16) ^ ((prow & 7) << 4)));
      }
      #pragma unroll
      for (int ei = 0; ei < 4; ei++){
        int vrow = ei*16 + lr;
        bf16x8 vf = *(const bf16x8*)((const char*)VTs + vrow*128 + ((kk*64 + lg*16) ^ ((vrow & 7) << 4)));
        #pragma unroll
        for (int mi = 0; mi < 2; mi++)
          oa[mi][ei] = __builtin_amdgcn_mfma_f32_16x16x32_bf16(pf[mi], vf, oa[mi][ei], 0, 0, 0);
      }
    }
  }

  // writeout: concat[b][q][h*64+e] bf16
  int b = bh >> 4, h = bh & 15;
  #pragma unroll
  for (int mi = 0; mi < 2; mi++)
    #pragma unroll
    for (int r = 0; r < 4; r++){
      float inv = 1.f / lsm[mi][r];
      int q = q0 + w*32 + mi*16 + lg*4 + r;
      size_t rowbase = (size_t)(b*2048 + q)*1024 + h*64;
      #pragma unroll
      for (int ei = 0; ei < 4; ei++){
        int e = ei*16 + lr;
        cc[rowbase + e] = f2bf(oa[mi][ei][r] * inv);
      }
    }
}

// ---------------- launch ----------------
extern "C" void kernel_launch(void* const* d_in, const int* in_sizes, int n_in,
                              void* d_out, int out_size, void* d_ws, size_t ws_size,
                              hipStream_t stream){
  const float* query = (const float*)d_in[0];
  const float* key_i = (const float*)d_in[1];
  const float* value = (const float*)d_in[2];
  const float* Wq = (const float*)d_in[3];
  const float* bq = (const float*)d_in[4];
  const float* Wk = (const float*)d_in[5];
  const float* bk = (const float*)d_in[6];
  const float* Wv = (const float*)d_in[7];
  const float* bv = (const float*)d_in[8];
  const float* Wo = (const float*)d_in[9];
  const float* bo = (const float*)d_in[10];
  const int* mask = (const int*)d_in[11];

  char* ws = (char*)d_ws;
  const size_t ACT = 8388608;   // 4096*1024 bf16
  unsigned short* Xq  = (unsigned short*)(ws + 0*ACT);
  unsigned short* Xk  = (unsigned short*)(ws + 1*ACT);
  unsigned short* Xv  = (unsigned short*)(ws + 2*ACT);
  unsigned short* qh  = (unsigned short*)(ws + 3*ACT);  // [B,H,S,DH]
  unsigned short* kh  = (unsigned short*)(ws + 4*ACT);
  unsigned short* vh  = (unsigned short*)(ws + 5*ACT);
  unsigned short* cc  = (unsigned short*)(ws + 6*ACT);  // concat [B,S,D]
  unsigned short* WqT = (unsigned short*)(ws + 7*ACT);            // [1024][1024] bf16
  unsigned short* WkT = (unsigned short*)(ws + 7*ACT + 2097152);
  unsigned short* WvT = (unsigned short*)(ws + 7*ACT + 4194304);
  unsigned short* WoT = (unsigned short*)(ws + 7*ACT + 6291456);

  convertx<<<2048, 256, 0, stream>>>(query, Xq, 524288);
  convertx<<<2048, 256, 0, stream>>>(key_i, Xk, 524288);
  convertx<<<2048, 256, 0, stream>>>(value, Xv, 524288);

  transpose_bf16<<<dim3(16,1,16), 256, 0, stream>>>(Wq, WqT, 1024, 64, 65536, 65536);
  transpose_bf16<<<dim3(16,1,16), 256, 0, stream>>>(Wk, WkT, 1024, 64, 65536, 65536);
  transpose_bf16<<<dim3(16,1,16), 256, 0, stream>>>(Wv, WvT, 1024, 64, 65536, 65536);
  transpose_bf16<<<dim3(16,16,1), 256, 0, stream>>>(Wo, WoT, 1024, 1024, 0, 0);

  // q projection: fold 1/sqrt(DH)=0.125 into output (applies to bias too, matching (q+b)/8)
  gemm_bt<0><<<dim3(8,32), 256, 0, stream>>>(Xq, WqT, bq, qh, 4096, 1024, 1024, 0.125f);
  gemm_bt<0><<<dim3(8,32), 256, 0, stream>>>(Xk, WkT, bk, kh, 4096, 1024, 1024, 1.0f);
  gemm_bt<0><<<dim3(8,32), 256, 0, stream>>>(Xv, WvT, bv, vh, 4096, 1024, 1024, 1.0f);

  attn_fwd<<<dim3(16,32), 256, 0, stream>>>(qh, kh, vh, cc, mask);

  gemm_bt<1><<<dim3(8,32), 256, 0, stream>>>(cc, WoT, bo, d_out, 4096, 1024, 1024, 1.0f);
}

// Round 8
// 359.332 us; speedup vs baseline: 1.0137x; 1.0137x over previous
//
#include <hip/hip_runtime.h>

// MultiHeadAttention: B=2, S=2048, D=1024, H=16, DH=64, causal.
// R4: attn QBLK 128->64 (4 blocks/CU), fused QKV projection GEMM (z=3), fused converts.

typedef short bf16x8 __attribute__((ext_vector_type(8)));
typedef float f32x4 __attribute__((ext_vector_type(4)));

__device__ __forceinline__ unsigned short f2bf(float f){
  unsigned int u = __builtin_bit_cast(unsigned int, f);
  u = (u + 0x7fffu + ((u >> 16) & 1u)) >> 16;
  return (unsigned short)u;
}

__device__ __forceinline__ void gld_lds16(const void* src, void* dst){
  __builtin_amdgcn_global_load_lds((const __attribute__((address_space(1))) unsigned int*)src,
                                   (__attribute__((address_space(3))) unsigned int*)dst,
                                   16, 0, 0);
}

// Stage a [rows][2^rowb_lg2 bytes] bf16 tile from global into LDS (linear dest).
// If swz: source pre-swizzled so swizzled ds_reads (byte ^ ((row&7)<<4)) see logical data.
__device__ __forceinline__ void stage_lds(const char* gtile, size_t growb, char* lds,
                                          int tid, int rowb_lg2, int swz, int tilebytes){
  int w = tid >> 6;
  for (int c = 0; c < tilebytes; c += 4096){
    int o = c + tid*16;
    int row = o >> rowb_lg2;
    int colb = o & ((1 << rowb_lg2) - 1);
    if (swz) colb ^= ((row & 7) << 4);
    gld_lds16(gtile + (size_t)row*growb + colb, lds + c + w*1024);
  }
}

// ---------------- fused fp32 -> bf16 convert for q,k,v (8 elems/thread) ----------------
__global__ __launch_bounds__(256) void convert3(const float* __restrict__ a,
                                                const float* __restrict__ b,
                                                const float* __restrict__ c,
                                                unsigned short* __restrict__ outa,
                                                unsigned short* __restrict__ outb,
                                                unsigned short* __restrict__ outc){
  int i = blockIdx.x*blockDim.x + threadIdx.x;     // [0, 3*524288)
  int seg = i >> 19, il = i & 524287;
  const float* in = seg==0 ? a : (seg==1 ? b : c);
  unsigned short* out = seg==0 ? outa : (seg==1 ? outb : outc);
  const float4* p = (const float4*)in;
  float4 x = p[2*il], y = p[2*il+1];
  uint4 o;
  o.x = (unsigned int)f2bf(x.x) | ((unsigned int)f2bf(x.y) << 16);
  o.y = (unsigned int)f2bf(x.z) | ((unsigned int)f2bf(x.w) << 16);
  o.z = (unsigned int)f2bf(y.x) | ((unsigned int)f2bf(y.y) << 16);
  o.w = (unsigned int)f2bf(y.z) | ((unsigned int)f2bf(y.w) << 16);
  ((uint4*)out)[il] = o;
}

// ---------------- transpose fp32 [R][C] -> bf16 [C][R], per-matrix z ----------------
__global__ __launch_bounds__(256) void transpose_bf16(const float* __restrict__ in,
                                                      unsigned short* __restrict__ out,
                                                      int R, int C,
                                                      size_t in_mstride, size_t out_mstride){
  __shared__ unsigned short tile[64][66];
  int t = threadIdx.x;
  int r0 = blockIdx.x*64, c0 = blockIdx.y*64;
  const float* inm = in + (size_t)blockIdx.z*in_mstride;
  unsigned short* outm = out + (size_t)blockIdx.z*out_mstride;
  int j = t & 63, i0 = (t >> 6)*16;
  #pragma unroll
  for (int ii = 0; ii < 16; ii++){
    int i = i0 + ii;
    tile[i][j] = f2bf(inm[(size_t)(r0+i)*C + c0 + j]);
  }
  __syncthreads();
  #pragma unroll
  for (int ii = 0; ii < 16; ii++){
    int i = i0 + ii;
    outm[(size_t)(c0+i)*R + r0 + j] = tile[j][i];
  }
}

// ---------------- GEMM core body (m97 structure), shared by both GEMM kernels ----------------
// C[M=4096, N=1024, K=1024]; A row-major bf16, BT row-major bf16 [N][K].
// EPI=0: bf16 out per-head layout; EPI=1: fp32 row-major out.
template<int EPI>
__device__ __forceinline__ void gemm_body(const unsigned short* A, const unsigned short* BT,
                                          const float* bias, void* outp, float scale,
                                          unsigned short (*lA)[128*32], unsigned short (*lB)[128*32]){
  const int K = 1024, N = 1024;
  int tid = threadIdx.x, lane = tid & 63, w = tid >> 6;
  int bn = blockIdx.x*128, bm = blockIdx.y*128;
  int wm = (w >> 1)*64, wn = (w & 1)*64;
  int lr = lane & 15;
  int lkb = (lane >> 4)*16;
  const char* Ab = (const char*)(A + (size_t)bm*K);
  const char* Bb = (const char*)(BT + (size_t)bn*K);
  size_t grow = (size_t)K*2;
  int nk = K >> 5;

  f32x4 zf = {0.f,0.f,0.f,0.f};
  f32x4 acc[4][4];
  #pragma unroll
  for (int mi = 0; mi < 4; mi++)
    #pragma unroll
    for (int ni = 0; ni < 4; ni++) acc[mi][ni] = zf;

  stage_lds(Ab, grow, (char*)lA[0], tid, 6, 0, 8192);
  stage_lds(Bb, grow, (char*)lB[0], tid, 6, 0, 8192);
  __syncthreads();
  int cur = 0;
  for (int kt = 0; kt < nk; kt++){
    if (kt + 1 < nk){
      stage_lds(Ab + (size_t)(kt+1)*64, grow, (char*)lA[cur^1], tid, 6, 0, 8192);
      stage_lds(Bb + (size_t)(kt+1)*64, grow, (char*)lB[cur^1], tid, 6, 0, 8192);
    }
    const char* pa = (const char*)lA[cur];
    const char* pb = (const char*)lB[cur];
    bf16x8 af[4], bfr[4];
    #pragma unroll
    for (int mi = 0; mi < 4; mi++)
      af[mi] = *(const bf16x8*)(pa + (wm + mi*16 + lr)*64 + lkb);
    #pragma unroll
    for (int ni = 0; ni < 4; ni++)
      bfr[ni] = *(const bf16x8*)(pb + (wn + ni*16 + lr)*64 + lkb);
    #pragma unroll
    for (int mi = 0; mi < 4; mi++)
      #pragma unroll
      for (int ni = 0; ni < 4; ni++)
        acc[mi][ni] = __builtin_amdgcn_mfma_f32_16x16x32_bf16(af[mi], bfr[ni], acc[mi][ni], 0, 0, 0);
    __syncthreads();
    cur ^= 1;
  }

  #pragma unroll
  for (int mi = 0; mi < 4; mi++)
    #pragma unroll
    for (int ni = 0; ni < 4; ni++)
      #pragma unroll
      for (int r = 0; r < 4; r++){
        int row = bm + wm + mi*16 + (lane >> 4)*4 + r;
        int col = bn + wn + ni*16 + (lane & 15);
        float v = acc[mi][ni][r] + bias[col];
        if (EPI == 0){
          v *= scale;
          unsigned short* o = (unsigned short*)outp;
          o[(size_t)((row >> 11)*16 + (col >> 6))*131072 + (size_t)(row & 2047)*64 + (col & 63)] = f2bf(v);
        } else {
          float* o = (float*)outp;
          o[(size_t)row*N + col] = v;
        }
      }
}

// fused QKV projection: blockIdx.z selects (X, W^T, bias, out, scale)
__global__ __launch_bounds__(256) void gemm_qkv(const unsigned short* __restrict__ Xq,
                                                const unsigned short* __restrict__ Xk,
                                                const unsigned short* __restrict__ Xv,
                                                const unsigned short* __restrict__ WqT,
                                                const unsigned short* __restrict__ WkT,
                                                const unsigned short* __restrict__ WvT,
                                                const float* __restrict__ bq,
                                                const float* __restrict__ bk,
                                                const float* __restrict__ bv,
                                                unsigned short* __restrict__ oq,
                                                unsigned short* __restrict__ ok,
                                                unsigned short* __restrict__ ov){
  __shared__ __align__(16) unsigned short lA[2][128*32];
  __shared__ __align__(16) unsigned short lB[2][128*32];
  int z = blockIdx.z;
  const unsigned short* A  = z==0 ? Xq  : (z==1 ? Xk  : Xv);
  const unsigned short* BT = z==0 ? WqT : (z==1 ? WkT : WvT);
  const float* bias        = z==0 ? bq  : (z==1 ? bk  : bv);
  unsigned short* out      = z==0 ? oq  : (z==1 ? ok  : ov);
  float scale = z==0 ? 0.125f : 1.0f;
  gemm_body<0>(A, BT, bias, out, scale, lA, lB);
}

// output GEMM (fp32 out)
__global__ __launch_bounds__(256) void gemm_out(const unsigned short* __restrict__ A,
                                                const unsigned short* __restrict__ BT,
                                                const float* __restrict__ bias,
                                                float* __restrict__ outp){
  __shared__ __align__(16) unsigned short lA[2][128*32];
  __shared__ __align__(16) unsigned short lB[2][128*32];
  gemm_body<1>(A, BT, bias, outp, 1.0f, lA, lB);
}

// ---------------- flash attention, causal ----------------
// grid: (S/64, B*H). 4 waves x 16 q-rows. KV tiles of 64. concat out bf16 [B,S,H*DH].
__global__ __launch_bounds__(256) void attn_fwd(const unsigned short* __restrict__ qh,
                                                const unsigned short* __restrict__ kh,
                                                const unsigned short* __restrict__ vh,
                                                unsigned short* __restrict__ cc,
                                                const int* __restrict__ maskp){
  __shared__ __align__(16) unsigned short Qs[64*64];    // 8 KB, swizzled
  __shared__ __align__(16) unsigned short Ks[64*64];    // 8 KB, swizzled
  __shared__ __align__(16) unsigned short VTs[64*64];   // 8 KB, V^T, swizzled
  __shared__ __align__(16) unsigned short Ps[4][16*64]; // 8 KB, per-wave P, swizzled
  int tid = threadIdx.x, lane = tid & 63, w = tid >> 6;
  int lg = lane >> 4, lr = lane & 15;
  int qt = blockIdx.x, bh = blockIdx.y;
  size_t base = (size_t)bh * (2048*64);
  const unsigned short* Q = qh + base;
  const unsigned short* K = kh + base;
  const unsigned short* V = vh + base;
  int q0 = qt*64;
  int causal = *maskp;

  stage_lds((const char*)(Q + (size_t)q0*64), 128, (char*)Qs, tid, 7, 1, 8192);
  __syncthreads();

  bf16x8 qf[2];
  #pragma unroll
  for (int kk = 0; kk < 2; kk++){
    int row = w*16 + lr;
    qf[kk] = *(const bf16x8*)((const char*)Qs + row*128 + ((kk*64 + lg*16) ^ ((row & 7) << 4)));
  }

  f32x4 zf = {0.f,0.f,0.f,0.f};
  f32x4 oa[4];
  float mr[4], lsm[4];
  #pragma unroll
  for (int ei = 0; ei < 4; ei++) oa[ei] = zf;
  #pragma unroll
  for (int r = 0; r < 4; r++){ mr[r] = -1e30f; lsm[r] = 0.f; }

  int nt = causal ? (qt + 1) : 32;
  int wq0 = q0 + w*16;

  for (int t = 0; t < nt; t++){
    __syncthreads();   // prev-iter K/V reads done before restage
    stage_lds((const char*)(K + (size_t)t*4096), 128, (char*)Ks, tid, 7, 1, 8192);
    // reg-stage V transposed into VTs (coalesced global read, swizzled 2B LDS writes)
    #pragma unroll
    for (int c = 0; c < 2; c++){
      int o = c*4096 + tid*16;
      uint4 vvv = *(const uint4*)((const char*)V + (size_t)t*8192 + o);
      int kv = o >> 7;
      int e0 = (o & 127) >> 1;
      unsigned int uu[4] = {vvv.x, vvv.y, vvv.z, vvv.w};
      #pragma unroll
      for (int j = 0; j < 4; j++){
        int e1 = e0 + 2*j, e2 = e1 + 1;
        *(unsigned short*)((char*)VTs + e1*128 + ((kv*2) ^ ((e1 & 7) << 4))) = (unsigned short)(uu[j] & 0xffffu);
        *(unsigned short*)((char*)VTs + e2*128 + ((kv*2) ^ ((e2 & 7) << 4))) = (unsigned short)(uu[j] >> 16);
      }
    }
    __syncthreads();   // staging visible to all waves

    if (causal && (t*64 > wq0 + 15)) continue;   // fully-masked for this wave

    // S = Q K^T  (scale folded into q projection)
    f32x4 sc[4];
    #pragma unroll
    for (int ni = 0; ni < 4; ni++) sc[ni] = zf;
    #pragma unroll
    for (int kk = 0; kk < 2; kk++)
      #pragma unroll
      for (int ni = 0; ni < 4; ni++){
        int krow = ni*16 + lr;
        bf16x8 kf = *(const bf16x8*)((const char*)Ks + krow*128 + ((kk*64 + lg*16) ^ ((krow & 7) << 4)));
        sc[ni] = __builtin_amdgcn_mfma_f32_16x16x32_bf16(qf[kk], kf, sc[ni], 0, 0, 0);
      }

    if (causal && (t*64 + 63 > wq0)){
      #pragma unroll
      for (int ni = 0; ni < 4; ni++)
        #pragma unroll
        for (int r = 0; r < 4; r++){
          int qrow = wq0 + lg*4 + r;
          int kvc  = t*64 + ni*16 + lr;
          if (kvc > qrow) sc[ni][r] = -1e9f;
        }
    }

    // online softmax (row owned by 16 lanes sharing lg; reduce over lane bits 0-3)
    #pragma unroll
    for (int r = 0; r < 4; r++){
      float mx = fmaxf(fmaxf(sc[0][r], sc[1][r]), fmaxf(sc[2][r], sc[3][r]));
      #pragma unroll
      for (int off = 1; off < 16; off <<= 1)
        mx = fmaxf(mx, __shfl_xor(mx, off, 64));
      float mo = mr[r];
      float mn = fmaxf(mo, mx);
      mr[r] = mn;
      float alpha = __expf(mo - mn);
      float psum = 0.f;
      #pragma unroll
      for (int ni = 0; ni < 4; ni++){
        float p = __expf(sc[ni][r] - mn);
        sc[ni][r] = p;
        psum += p;
      }
      #pragma unroll
      for (int off = 1; off < 16; off <<= 1)
        psum += __shfl_xor(psum, off, 64);
      lsm[r] = lsm[r]*alpha + psum;
      #pragma unroll
      for (int ei = 0; ei < 4; ei++) oa[ei][r] *= alpha;   // component r only
    }

    // P (bf16) -> per-wave LDS (swizzled rows)
    #pragma unroll
    for (int ni = 0; ni < 4; ni++)
      #pragma unroll
      for (int r = 0; r < 4; r++){
        int prow = lg*4 + r;
        int pcb = (ni*16 + lr)*2;
        *(unsigned short*)((char*)Ps[w] + prow*128 + (pcb ^ ((prow & 7) << 4))) = f2bf(sc[ni][r]);
      }

    // O += P @ V  (DS ops in-order within wave; Ps[w] wave-private)
    #pragma unroll
    for (int kk = 0; kk < 2; kk++){
      bf16x8 pf = *(const bf16x8*)((const char*)Ps[w] + lr*128 + ((kk*64 + lg*16) ^ ((lr & 7) << 4)));
      #pragma unroll
      for (int ei = 0; ei < 4; ei++){
        int vrow = ei*16 + lr;
        bf16x8 vf = *(const bf16x8*)((const char*)VTs + vrow*128 + ((kk*64 + lg*16) ^ ((vrow & 7) << 4)));
        oa[ei] = __builtin_amdgcn_mfma_f32_16x16x32_bf16(pf, vf, oa[ei], 0, 0, 0);
      }
    }
  }

  // writeout: concat[b][q][h*64+e] bf16
  int b = bh >> 4, h = bh & 15;
  #pragma unroll
  for (int r = 0; r < 4; r++){
    float inv = 1.f / lsm[r];
    int q = q0 + w*16 + lg*4 + r;
    size_t rowbase = (size_t)(b*2048 + q)*1024 + h*64;
    #pragma unroll
    for (int ei = 0; ei < 4; ei++){
      int e = ei*16 + lr;
      cc[rowbase + e] = f2bf(oa[ei][r] * inv);
    }
  }
}

// ---------------- launch ----------------
extern "C" void kernel_launch(void* const* d_in, const int* in_sizes, int n_in,
                              void* d_out, int out_size, void* d_ws, size_t ws_size,
                              hipStream_t stream){
  const float* query = (const float*)d_in[0];
  const float* key_i = (const float*)d_in[1];
  const float* value = (const float*)d_in[2];
  const float* Wq = (const float*)d_in[3];
  const float* bq = (const float*)d_in[4];
  const float* Wk = (const float*)d_in[5];
  const float* bk = (const float*)d_in[6];
  const float* Wv = (const float*)d_in[7];
  const float* bv = (const float*)d_in[8];
  const float* Wo = (const float*)d_in[9];
  const float* bo = (const float*)d_in[10];
  const int* mask = (const int*)d_in[11];

  char* ws = (char*)d_ws;
  const size_t ACT = 8388608;   // 4096*1024 bf16
  unsigned short* Xq  = (unsigned short*)(ws + 0*ACT);
  unsigned short* Xk  = (unsigned short*)(ws + 1*ACT);
  unsigned short* Xv  = (unsigned short*)(ws + 2*ACT);
  unsigned short* qh  = (unsigned short*)(ws + 3*ACT);  // [B,H,S,DH]
  unsigned short* kh  = (unsigned short*)(ws + 4*ACT);
  unsigned short* vh  = (unsigned short*)(ws + 5*ACT);
  unsigned short* cc  = (unsigned short*)(ws + 6*ACT);  // concat [B,S,D]
  unsigned short* WqT = (unsigned short*)(ws + 7*ACT);            // [1024][1024] bf16
  unsigned short* WkT = (unsigned short*)(ws + 7*ACT + 2097152);
  unsigned short* WvT = (unsigned short*)(ws + 7*ACT + 4194304);
  unsigned short* WoT = (unsigned short*)(ws + 7*ACT + 6291456);

  convert3<<<6144, 256, 0, stream>>>(query, key_i, value, Xq, Xk, Xv);

  transpose_bf16<<<dim3(16,1,16), 256, 0, stream>>>(Wq, WqT, 1024, 64, 65536, 65536);
  transpose_bf16<<<dim3(16,1,16), 256, 0, stream>>>(Wk, WkT, 1024, 64, 65536, 65536);
  transpose_bf16<<<dim3(16,1,16), 256, 0, stream>>>(Wv, WvT, 1024, 64, 65536, 65536);
  transpose_bf16<<<dim3(16,16,1), 256, 0, stream>>>(Wo, WoT, 1024, 1024, 0, 0);

  gemm_qkv<<<dim3(8,32,3), 256, 0, stream>>>(Xq, Xk, Xv, WqT, WkT, WvT, bq, bk, bv, qh, kh, vh);

  attn_fwd<<<dim3(32,32), 256, 0, stream>>>(qh, kh, vh, cc, mask);

  gemm_out<<<dim3(8,32), 256, 0, stream>>>(cc, WoT, bo, (float*)d_out);
}

// Round 10
// 336.732 us; speedup vs baseline: 1.0818x; 1.0671x over previous
//
#include <hip/hip_runtime.h>

// MultiHeadAttention: B=2, S=2048, D=1024, H=16, DH=64, causal.
// R5: attn restructured -> no barriers, no in-loop staging: K/V^T fragments read
// directly from global (L2-resident), V pre-transposed once, bh->XCD pinning,
// deepest-first dispatch. QKV GEMM fusion + convert fusion kept from R4.

typedef short bf16x8 __attribute__((ext_vector_type(8)));
typedef float f32x4 __attribute__((ext_vector_type(4)));

__device__ __forceinline__ unsigned short f2bf(float f){
  unsigned int u = __builtin_bit_cast(unsigned int, f);
  u = (u + 0x7fffu + ((u >> 16) & 1u)) >> 16;
  return (unsigned short)u;
}

__device__ __forceinline__ void gld_lds16(const void* src, void* dst){
  __builtin_amdgcn_global_load_lds((const __attribute__((address_space(1))) unsigned int*)src,
                                   (__attribute__((address_space(3))) unsigned int*)dst,
                                   16, 0, 0);
}

__device__ __forceinline__ void stage_lds(const char* gtile, size_t growb, char* lds,
                                          int tid, int rowb_lg2, int swz, int tilebytes){
  int w = tid >> 6;
  for (int c = 0; c < tilebytes; c += 4096){
    int o = c + tid*16;
    int row = o >> rowb_lg2;
    int colb = o & ((1 << rowb_lg2) - 1);
    if (swz) colb ^= ((row & 7) << 4);
    gld_lds16(gtile + (size_t)row*growb + colb, lds + c + w*1024);
  }
}

// ---------------- fused fp32 -> bf16 convert for q,k,v (8 elems/thread) ----------------
__global__ __launch_bounds__(256) void convert3(const float* __restrict__ a,
                                                const float* __restrict__ b,
                                                const float* __restrict__ c,
                                                unsigned short* __restrict__ outa,
                                                unsigned short* __restrict__ outb,
                                                unsigned short* __restrict__ outc){
  int i = blockIdx.x*blockDim.x + threadIdx.x;     // [0, 3*524288)
  int seg = i >> 19, il = i & 524287;
  const float* in = seg==0 ? a : (seg==1 ? b : c);
  unsigned short* out = seg==0 ? outa : (seg==1 ? outb : outc);
  const float4* p = (const float4*)in;
  float4 x = p[2*il], y = p[2*il+1];
  uint4 o;
  o.x = (unsigned int)f2bf(x.x) | ((unsigned int)f2bf(x.y) << 16);
  o.y = (unsigned int)f2bf(x.z) | ((unsigned int)f2bf(x.w) << 16);
  o.z = (unsigned int)f2bf(y.x) | ((unsigned int)f2bf(y.y) << 16);
  o.w = (unsigned int)f2bf(y.z) | ((unsigned int)f2bf(y.w) << 16);
  ((uint4*)out)[il] = o;
}

// ---------------- transpose fp32 [R][C] -> bf16 [C][R], per-matrix z ----------------
__global__ __launch_bounds__(256) void transpose_bf16(const float* __restrict__ in,
                                                      unsigned short* __restrict__ out,
                                                      int R, int C,
                                                      size_t in_mstride, size_t out_mstride){
  __shared__ unsigned short tile[64][66];
  int t = threadIdx.x;
  int r0 = blockIdx.x*64, c0 = blockIdx.y*64;
  const float* inm = in + (size_t)blockIdx.z*in_mstride;
  unsigned short* outm = out + (size_t)blockIdx.z*out_mstride;
  int j = t & 63, i0 = (t >> 6)*16;
  #pragma unroll
  for (int ii = 0; ii < 16; ii++){
    int i = i0 + ii;
    tile[i][j] = f2bf(inm[(size_t)(r0+i)*C + c0 + j]);
  }
  __syncthreads();
  #pragma unroll
  for (int ii = 0; ii < 16; ii++){
    int i = i0 + ii;
    outm[(size_t)(c0+i)*R + r0 + j] = tile[j][i];
  }
}

// ---------------- transpose bf16: vh [BH][2048][64] -> vt [BH][64][2048] ----------------
__global__ __launch_bounds__(256) void transpose_v(const unsigned short* __restrict__ in,
                                                   unsigned short* __restrict__ out){
  __shared__ unsigned short tile[64][66];
  int t = threadIdx.x;
  int s0 = blockIdx.x*64;
  const unsigned short* inm = in + (size_t)blockIdx.y*131072;
  unsigned short* outm = out + (size_t)blockIdx.y*131072;
  int j = t & 63, i0 = (t >> 6)*16;
  #pragma unroll
  for (int ii = 0; ii < 16; ii++){
    int i = i0 + ii;                           // s offset within tile
    tile[i][j] = inm[(size_t)(s0+i)*64 + j];   // coalesced 128B rows
  }
  __syncthreads();
  #pragma unroll
  for (int ii = 0; ii < 16; ii++){
    int i = i0 + ii;                           // e (out row)
    outm[(size_t)i*2048 + s0 + j] = tile[j][i]; // coalesced 128B rows
  }
}

// ---------------- GEMM core body (m97 structure) ----------------
// C[M=4096, N=1024, K=1024]; A row-major bf16, BT row-major bf16 [N][K].
// EPI=0: bf16 out per-head layout; EPI=1: fp32 row-major out.
template<int EPI>
__device__ __forceinline__ void gemm_body(const unsigned short* A, const unsigned short* BT,
                                          const float* bias, void* outp, float scale,
                                          unsigned short (*lA)[128*32], unsigned short (*lB)[128*32]){
  const int K = 1024, N = 1024;
  int tid = threadIdx.x, lane = tid & 63, w = tid >> 6;
  int bn = blockIdx.x*128, bm = blockIdx.y*128;
  int wm = (w >> 1)*64, wn = (w & 1)*64;
  int lr = lane & 15;
  int lkb = (lane >> 4)*16;
  const char* Ab = (const char*)(A + (size_t)bm*K);
  const char* Bb = (const char*)(BT + (size_t)bn*K);
  size_t grow = (size_t)K*2;
  int nk = K >> 5;

  f32x4 zf = {0.f,0.f,0.f,0.f};
  f32x4 acc[4][4];
  #pragma unroll
  for (int mi = 0; mi < 4; mi++)
    #pragma unroll
    for (int ni = 0; ni < 4; ni++) acc[mi][ni] = zf;

  stage_lds(Ab, grow, (char*)lA[0], tid, 6, 0, 8192);
  stage_lds(Bb, grow, (char*)lB[0], tid, 6, 0, 8192);
  __syncthreads();
  int cur = 0;
  for (int kt = 0; kt < nk; kt++){
    if (kt + 1 < nk){
      stage_lds(Ab + (size_t)(kt+1)*64, grow, (char*)lA[cur^1], tid, 6, 0, 8192);
      stage_lds(Bb + (size_t)(kt+1)*64, grow, (char*)lB[cur^1], tid, 6, 0, 8192);
    }
    const char* pa = (const char*)lA[cur];
    const char* pb = (const char*)lB[cur];
    bf16x8 af[4], bfr[4];
    #pragma unroll
    for (int mi = 0; mi < 4; mi++)
      af[mi] = *(const bf16x8*)(pa + (wm + mi*16 + lr)*64 + lkb);
    #pragma unroll
    for (int ni = 0; ni < 4; ni++)
      bfr[ni] = *(const bf16x8*)(pb + (wn + ni*16 + lr)*64 + lkb);
    #pragma unroll
    for (int mi = 0; mi < 4; mi++)
      #pragma unroll
      for (int ni = 0; ni < 4; ni++)
        acc[mi][ni] = __builtin_amdgcn_mfma_f32_16x16x32_bf16(af[mi], bfr[ni], acc[mi][ni], 0, 0, 0);
    __syncthreads();
    cur ^= 1;
  }

  #pragma unroll
  for (int mi = 0; mi < 4; mi++)
    #pragma unroll
    for (int ni = 0; ni < 4; ni++)
      #pragma unroll
      for (int r = 0; r < 4; r++){
        int row = bm + wm + mi*16 + (lane >> 4)*4 + r;
        int col = bn + wn + ni*16 + (lane & 15);
        float v = acc[mi][ni][r] + bias[col];
        if (EPI == 0){
          v *= scale;
          unsigned short* o = (unsigned short*)outp;
          o[(size_t)((row >> 11)*16 + (col >> 6))*131072 + (size_t)(row & 2047)*64 + (col & 63)] = f2bf(v);
        } else {
          float* o = (float*)outp;
          o[(size_t)row*N + col] = v;
        }
      }
}

// fused QKV projection: blockIdx.z selects (X, W^T, bias, out, scale)
__global__ __launch_bounds__(256) void gemm_qkv(const unsigned short* __restrict__ Xq,
                                                const unsigned short* __restrict__ Xk,
                                                const unsigned short* __restrict__ Xv,
                                                const unsigned short* __restrict__ WqT,
                                                const unsigned short* __restrict__ WkT,
                                                const unsigned short* __restrict__ WvT,
                                                const float* __restrict__ bq,
                                                const float* __restrict__ bk,
                                                const float* __restrict__ bv,
                                                unsigned short* __restrict__ oq,
                                                unsigned short* __restrict__ ok,
                                                unsigned short* __restrict__ ov){
  __shared__ __align__(16) unsigned short lA[2][128*32];
  __shared__ __align__(16) unsigned short lB[2][128*32];
  int z = blockIdx.z;
  const unsigned short* A  = z==0 ? Xq  : (z==1 ? Xk  : Xv);
  const unsigned short* BT = z==0 ? WqT : (z==1 ? WkT : WvT);
  const float* bias        = z==0 ? bq  : (z==1 ? bk  : bv);
  unsigned short* out      = z==0 ? oq  : (z==1 ? ok  : ov);
  float scale = z==0 ? 0.125f : 1.0f;
  gemm_body<0>(A, BT, bias, out, scale, lA, lB);
}

// output GEMM (fp32 out)
__global__ __launch_bounds__(256) void gemm_out(const unsigned short* __restrict__ A,
                                                const unsigned short* __restrict__ BT,
                                                const float* __restrict__ bias,
                                                float* __restrict__ outp){
  __shared__ __align__(16) unsigned short lA[2][128*32];
  __shared__ __align__(16) unsigned short lB[2][128*32];
  gemm_body<1>(A, BT, bias, outp, 1.0f, lA, lB);
}

// ---------------- flash attention v2: no barriers, direct-global K/VT ----------------
// grid: 1024 blocks x 256 threads. bid: bh = bid&31 (bh&7 pins XCD), qquad = 31-(bid>>5)
// (deepest first). Wave w owns q-group g = qquad*4+w -> q rows [g*16, g*16+16).
__global__ __launch_bounds__(256) void attn_fwd2(const unsigned short* __restrict__ qh,
                                                 const unsigned short* __restrict__ kh,
                                                 const unsigned short* __restrict__ vt,
                                                 unsigned short* __restrict__ cc,
                                                 const int* __restrict__ maskp){
  __shared__ __align__(16) unsigned short Ps[4][16*64]; // 8 KB, per-wave P, swizzled
  int tid = threadIdx.x, lane = tid & 63, w = tid >> 6;
  int lg = lane >> 4, lr = lane & 15;
  int bid = blockIdx.x;
  int bh = bid & 31;
  int qquad = 31 - (bid >> 5);
  int causal = *maskp;
  int g = qquad*4 + w;
  int wq0 = g*16;
  const char* Q  = (const char*)(qh + (size_t)bh*131072);
  const char* K  = (const char*)(kh + (size_t)bh*131072);
  const char* VT = (const char*)(vt + (size_t)bh*131072);

  // Q fragments: row wq0+lr (128B rows), k-bytes kk*64 + lg*16
  bf16x8 qf[2];
  #pragma unroll
  for (int kk = 0; kk < 2; kk++)
    qf[kk] = *(const bf16x8*)(Q + (size_t)(wq0 + lr)*128 + kk*64 + lg*16);

  f32x4 zf = {0.f,0.f,0.f,0.f};
  f32x4 oa[4];
  float mr[4], lsm[4];
  #pragma unroll
  for (int ei = 0; ei < 4; ei++) oa[ei] = zf;
  #pragma unroll
  for (int r = 0; r < 4; r++){ mr[r] = -1e30f; lsm[r] = 0.f; }

  int nt = causal ? (qquad + 1) : 32;

  for (int t = 0; t < nt; t++){
    // K fragments direct from global (L2-hot): rows t*64+ni*16+lr
    bf16x8 kf[2][4];
    #pragma unroll
    for (int kk = 0; kk < 2; kk++)
      #pragma unroll
      for (int ni = 0; ni < 4; ni++)
        kf[kk][ni] = *(const bf16x8*)(K + (size_t)(t*64 + ni*16 + lr)*128 + kk*64 + lg*16);

    // S = Q K^T (scale folded into q projection)
    f32x4 sc[4];
    #pragma unroll
    for (int ni = 0; ni < 4; ni++) sc[ni] = zf;
    #pragma unroll
    for (int kk = 0; kk < 2; kk++)
      #pragma unroll
      for (int ni = 0; ni < 4; ni++)
        sc[ni] = __builtin_amdgcn_mfma_f32_16x16x32_bf16(qf[kk], kf[kk][ni], sc[ni], 0, 0, 0);

    if (causal && (t*64 + 63 > wq0)){
      #pragma unroll
      for (int ni = 0; ni < 4; ni++)
        #pragma unroll
        for (int r = 0; r < 4; r++){
          int qrow = wq0 + lg*4 + r;
          int kvc  = t*64 + ni*16 + lr;
          if (kvc > qrow) sc[ni][r] = -1e9f;
        }
    }

    // online softmax (row owned by 16 lanes sharing lg; reduce over lane bits 0-3)
    #pragma unroll
    for (int r = 0; r < 4; r++){
      float mx = fmaxf(fmaxf(sc[0][r], sc[1][r]), fmaxf(sc[2][r], sc[3][r]));
      #pragma unroll
      for (int off = 1; off < 16; off <<= 1)
        mx = fmaxf(mx, __shfl_xor(mx, off, 64));
      float mo = mr[r];
      float mn = fmaxf(mo, mx);
      mr[r] = mn;
      float alpha = __expf(mo - mn);
      float psum = 0.f;
      #pragma unroll
      for (int ni = 0; ni < 4; ni++){
        float p = __expf(sc[ni][r] - mn);
        sc[ni][r] = p;
        psum += p;
      }
      #pragma unroll
      for (int off = 1; off < 16; off <<= 1)
        psum += __shfl_xor(psum, off, 64);
      lsm[r] = lsm[r]*alpha + psum;
      #pragma unroll
      for (int ei = 0; ei < 4; ei++) oa[ei][r] *= alpha;   // component r only
    }

    // P (bf16) -> per-wave LDS (swizzled rows); wave-private, no barrier needed
    #pragma unroll
    for (int ni = 0; ni < 4; ni++)
      #pragma unroll
      for (int r = 0; r < 4; r++){
        int prow = lg*4 + r;
        int pcb = (ni*16 + lr)*2;
        *(unsigned short*)((char*)Ps[w] + prow*128 + (pcb ^ ((prow & 7) << 4))) = f2bf(sc[ni][r]);
      }

    // O += P @ V : V^T fragments direct from global (rows e, 4096B row stride)
    #pragma unroll
    for (int kk = 0; kk < 2; kk++){
      bf16x8 pf = *(const bf16x8*)((const char*)Ps[w] + lr*128 + ((kk*64 + lg*16) ^ ((lr & 7) << 4)));
      #pragma unroll
      for (int ei = 0; ei < 4; ei++){
        bf16x8 vf = *(const bf16x8*)(VT + (size_t)(ei*16 + lr)*4096 + t*128 + kk*64 + lg*16);
        oa[ei] = __builtin_amdgcn_mfma_f32_16x16x32_bf16(pf, vf, oa[ei], 0, 0, 0);
      }
    }
  }

  // writeout: concat[b][q][h*64+e] bf16
  int b = bh >> 4, h = bh & 15;
  #pragma unroll
  for (int r = 0; r < 4; r++){
    float inv = 1.f / lsm[r];
    int q = wq0 + lg*4 + r;
    size_t rowbase = (size_t)(b*2048 + q)*1024 + h*64;
    #pragma unroll
    for (int ei = 0; ei < 4; ei++){
      int e = ei*16 + lr;
      cc[rowbase + e] = f2bf(oa[ei][r] * inv);
    }
  }
}

// ---------------- launch ----------------
extern "C" void kernel_launch(void* const* d_in, const int* in_sizes, int n_in,
                              void* d_out, int out_size, void* d_ws, size_t ws_size,
                              hipStream_t stream){
  const float* query = (const float*)d_in[0];
  const float* key_i = (const float*)d_in[1];
  const float* value = (const float*)d_in[2];
  const float* Wq = (const float*)d_in[3];
  const float* bq = (const float*)d_in[4];
  const float* Wk = (const float*)d_in[5];
  const float* bk = (const float*)d_in[6];
  const float* Wv = (const float*)d_in[7];
  const float* bv = (const float*)d_in[8];
  const float* Wo = (const float*)d_in[9];
  const float* bo = (const float*)d_in[10];
  const int* mask = (const int*)d_in[11];

  char* ws = (char*)d_ws;
  const size_t ACT = 8388608;   // 4096*1024 bf16
  unsigned short* Xq  = (unsigned short*)(ws + 0*ACT);
  unsigned short* Xk  = (unsigned short*)(ws + 1*ACT);
  unsigned short* Xv  = (unsigned short*)(ws + 2*ACT);
  unsigned short* qh  = (unsigned short*)(ws + 3*ACT);  // [B,H,S,DH]
  unsigned short* kh  = (unsigned short*)(ws + 4*ACT);
  unsigned short* vh  = (unsigned short*)(ws + 5*ACT);
  unsigned short* cc  = (unsigned short*)(ws + 6*ACT);  // concat [B,S,D]
  unsigned short* WqT = (unsigned short*)(ws + 7*ACT);            // [1024][1024] bf16
  unsigned short* WkT = (unsigned short*)(ws + 7*ACT + 2097152);
  unsigned short* WvT = (unsigned short*)(ws + 7*ACT + 4194304);
  unsigned short* WoT = (unsigned short*)(ws + 7*ACT + 6291456);
  unsigned short* vtr = Xq;  // [B,H,DH,S] V^T; reuses Xq slot (dead after gemm_qkv)

  convert3<<<6144, 256, 0, stream>>>(query, key_i, value, Xq, Xk, Xv);

  transpose_bf16<<<dim3(16,1,16), 256, 0, stream>>>(Wq, WqT, 1024, 64, 65536, 65536);
  transpose_bf16<<<dim3(16,1,16), 256, 0, stream>>>(Wk, WkT, 1024, 64, 65536, 65536);
  transpose_bf16<<<dim3(16,1,16), 256, 0, stream>>>(Wv, WvT, 1024, 64, 65536, 65536);
  transpose_bf16<<<dim3(16,16,1), 256, 0, stream>>>(Wo, WoT, 1024, 1024, 0, 0);

  gemm_qkv<<<dim3(8,32,3), 256, 0, stream>>>(Xq, Xk, Xv, WqT, WkT, WvT, bq, bk, bv, qh, kh, vh);

  transpose_v<<<dim3(32,32), 256, 0, stream>>>(vh, vtr);

  attn_fwd2<<<1024, 256, 0, stream>>>(qh, kh, vtr, cc, mask);

  gemm_out<<<dim3(8,32), 256, 0, stream>>>(cc, WoT, bo, (float*)d_out);
}

// Round 11
// 305.462 us; speedup vs baseline: 1.1925x; 1.1024x over previous
//
#include <hip/hip_runtime.h>

// MultiHeadAttention: B=2, S=2048, D=1024, H=16, DH=64, causal.
// R6: attn_fwd3 — paired q-tiles (p, 31-p): constant 33 tiles/block (perfect balance),
// shared K/V regs feed 2 chains (ILP x2, 32 MFMA per K/V load-set), K(t+1) reg prefetch,
// V issued at top of iter. No barriers, no in-loop LDS staging (from R5).

typedef short bf16x8 __attribute__((ext_vector_type(8)));
typedef float f32x4 __attribute__((ext_vector_type(4)));

__device__ __forceinline__ unsigned short f2bf(float f){
  unsigned int u = __builtin_bit_cast(unsigned int, f);
  u = (u + 0x7fffu + ((u >> 16) & 1u)) >> 16;
  return (unsigned short)u;
}

__device__ __forceinline__ void gld_lds16(const void* src, void* dst){
  __builtin_amdgcn_global_load_lds((const __attribute__((address_space(1))) unsigned int*)src,
                                   (__attribute__((address_space(3))) unsigned int*)dst,
                                   16, 0, 0);
}

__device__ __forceinline__ void stage_lds(const char* gtile, size_t growb, char* lds,
                                          int tid, int rowb_lg2, int swz, int tilebytes){
  int w = tid >> 6;
  for (int c = 0; c < tilebytes; c += 4096){
    int o = c + tid*16;
    int row = o >> rowb_lg2;
    int colb = o & ((1 << rowb_lg2) - 1);
    if (swz) colb ^= ((row & 7) << 4);
    gld_lds16(gtile + (size_t)row*growb + colb, lds + c + w*1024);
  }
}

// ---------------- fused fp32 -> bf16 convert for q,k,v ----------------
__global__ __launch_bounds__(256) void convert3(const float* __restrict__ a,
                                                const float* __restrict__ b,
                                                const float* __restrict__ c,
                                                unsigned short* __restrict__ outa,
                                                unsigned short* __restrict__ outb,
                                                unsigned short* __restrict__ outc){
  int i = blockIdx.x*blockDim.x + threadIdx.x;
  int seg = i >> 19, il = i & 524287;
  const float* in = seg==0 ? a : (seg==1 ? b : c);
  unsigned short* out = seg==0 ? outa : (seg==1 ? outb : outc);
  const float4* p = (const float4*)in;
  float4 x = p[2*il], y = p[2*il+1];
  uint4 o;
  o.x = (unsigned int)f2bf(x.x) | ((unsigned int)f2bf(x.y) << 16);
  o.y = (unsigned int)f2bf(x.z) | ((unsigned int)f2bf(x.w) << 16);
  o.z = (unsigned int)f2bf(y.x) | ((unsigned int)f2bf(y.y) << 16);
  o.w = (unsigned int)f2bf(y.z) | ((unsigned int)f2bf(y.w) << 16);
  ((uint4*)out)[il] = o;
}

// ---------------- transpose fp32 [R][C] -> bf16 [C][R] ----------------
__global__ __launch_bounds__(256) void transpose_bf16(const float* __restrict__ in,
                                                      unsigned short* __restrict__ out,
                                                      int R, int C,
                                                      size_t in_mstride, size_t out_mstride){
  __shared__ unsigned short tile[64][66];
  int t = threadIdx.x;
  int r0 = blockIdx.x*64, c0 = blockIdx.y*64;
  const float* inm = in + (size_t)blockIdx.z*in_mstride;
  unsigned short* outm = out + (size_t)blockIdx.z*out_mstride;
  int j = t & 63, i0 = (t >> 6)*16;
  #pragma unroll
  for (int ii = 0; ii < 16; ii++){
    int i = i0 + ii;
    tile[i][j] = f2bf(inm[(size_t)(r0+i)*C + c0 + j]);
  }
  __syncthreads();
  #pragma unroll
  for (int ii = 0; ii < 16; ii++){
    int i = i0 + ii;
    outm[(size_t)(c0+i)*R + r0 + j] = tile[j][i];
  }
}

// ---------------- transpose bf16: vh [BH][2048][64] -> vt [BH][64][2048] ----------------
__global__ __launch_bounds__(256) void transpose_v(const unsigned short* __restrict__ in,
                                                   unsigned short* __restrict__ out){
  __shared__ unsigned short tile[64][66];
  int t = threadIdx.x;
  int s0 = blockIdx.x*64;
  const unsigned short* inm = in + (size_t)blockIdx.y*131072;
  unsigned short* outm = out + (size_t)blockIdx.y*131072;
  int j = t & 63, i0 = (t >> 6)*16;
  #pragma unroll
  for (int ii = 0; ii < 16; ii++){
    int i = i0 + ii;
    tile[i][j] = inm[(size_t)(s0+i)*64 + j];
  }
  __syncthreads();
  #pragma unroll
  for (int ii = 0; ii < 16; ii++){
    int i = i0 + ii;
    outm[(size_t)i*2048 + s0 + j] = tile[j][i];
  }
}

// ---------------- GEMM core body (m97 structure) ----------------
template<int EPI>
__device__ __forceinline__ void gemm_body(const unsigned short* A, const unsigned short* BT,
                                          const float* bias, void* outp, float scale,
                                          unsigned short (*lA)[128*32], unsigned short (*lB)[128*32]){
  const int K = 1024, N = 1024;
  int tid = threadIdx.x, lane = tid & 63, w = tid >> 6;
  int bn = blockIdx.x*128, bm = blockIdx.y*128;
  int wm = (w >> 1)*64, wn = (w & 1)*64;
  int lr = lane & 15;
  int lkb = (lane >> 4)*16;
  const char* Ab = (const char*)(A + (size_t)bm*K);
  const char* Bb = (const char*)(BT + (size_t)bn*K);
  size_t grow = (size_t)K*2;
  int nk = K >> 5;

  f32x4 zf = {0.f,0.f,0.f,0.f};
  f32x4 acc[4][4];
  #pragma unroll
  for (int mi = 0; mi < 4; mi++)
    #pragma unroll
    for (int ni = 0; ni < 4; ni++) acc[mi][ni] = zf;

  stage_lds(Ab, grow, (char*)lA[0], tid, 6, 0, 8192);
  stage_lds(Bb, grow, (char*)lB[0], tid, 6, 0, 8192);
  __syncthreads();
  int cur = 0;
  for (int kt = 0; kt < nk; kt++){
    if (kt + 1 < nk){
      stage_lds(Ab + (size_t)(kt+1)*64, grow, (char*)lA[cur^1], tid, 6, 0, 8192);
      stage_lds(Bb + (size_t)(kt+1)*64, grow, (char*)lB[cur^1], tid, 6, 0, 8192);
    }
    const char* pa = (const char*)lA[cur];
    const char* pb = (const char*)lB[cur];
    bf16x8 af[4], bfr[4];
    #pragma unroll
    for (int mi = 0; mi < 4; mi++)
      af[mi] = *(const bf16x8*)(pa + (wm + mi*16 + lr)*64 + lkb);
    #pragma unroll
    for (int ni = 0; ni < 4; ni++)
      bfr[ni] = *(const bf16x8*)(pb + (wn + ni*16 + lr)*64 + lkb);
    #pragma unroll
    for (int mi = 0; mi < 4; mi++)
      #pragma unroll
      for (int ni = 0; ni < 4; ni++)
        acc[mi][ni] = __builtin_amdgcn_mfma_f32_16x16x32_bf16(af[mi], bfr[ni], acc[mi][ni], 0, 0, 0);
    __syncthreads();
    cur ^= 1;
  }

  #pragma unroll
  for (int mi = 0; mi < 4; mi++)
    #pragma unroll
    for (int ni = 0; ni < 4; ni++)
      #pragma unroll
      for (int r = 0; r < 4; r++){
        int row = bm + wm + mi*16 + (lane >> 4)*4 + r;
        int col = bn + wn + ni*16 + (lane & 15);
        float v = acc[mi][ni][r] + bias[col];
        if (EPI == 0){
          v *= scale;
          unsigned short* o = (unsigned short*)outp;
          o[(size_t)((row >> 11)*16 + (col >> 6))*131072 + (size_t)(row & 2047)*64 + (col & 63)] = f2bf(v);
        } else {
          float* o = (float*)outp;
          o[(size_t)row*N + col] = v;
        }
      }
}

// fused QKV projection
__global__ __launch_bounds__(256) void gemm_qkv(const unsigned short* __restrict__ Xq,
                                                const unsigned short* __restrict__ Xk,
                                                const unsigned short* __restrict__ Xv,
                                                const unsigned short* __restrict__ WqT,
                                                const unsigned short* __restrict__ WkT,
                                                const unsigned short* __restrict__ WvT,
                                                const float* __restrict__ bq,
                                                const float* __restrict__ bk,
                                                const float* __restrict__ bv,
                                                unsigned short* __restrict__ oq,
                                                unsigned short* __restrict__ ok,
                                                unsigned short* __restrict__ ov){
  __shared__ __align__(16) unsigned short lA[2][128*32];
  __shared__ __align__(16) unsigned short lB[2][128*32];
  int z = blockIdx.z;
  const unsigned short* A  = z==0 ? Xq  : (z==1 ? Xk  : Xv);
  const unsigned short* BT = z==0 ? WqT : (z==1 ? WkT : WvT);
  const float* bias        = z==0 ? bq  : (z==1 ? bk  : bv);
  unsigned short* out      = z==0 ? oq  : (z==1 ? ok  : ov);
  float scale = z==0 ? 0.125f : 1.0f;
  gemm_body<0>(A, BT, bias, out, scale, lA, lB);
}

// output GEMM (fp32 out)
__global__ __launch_bounds__(256) void gemm_out(const unsigned short* __restrict__ A,
                                                const unsigned short* __restrict__ BT,
                                                const float* __restrict__ bias,
                                                float* __restrict__ outp){
  __shared__ __align__(16) unsigned short lA[2][128*32];
  __shared__ __align__(16) unsigned short lB[2][128*32];
  gemm_body<1>(A, BT, bias, outp, 1.0f, lA, lB);
}

// ---------------- attn helpers ----------------
__device__ __forceinline__ void online_sm(f32x4* sc, float* mr, float* ls, f32x4* oa){
  #pragma unroll
  for (int r = 0; r < 4; r++){
    float mx = fmaxf(fmaxf(sc[0][r], sc[1][r]), fmaxf(sc[2][r], sc[3][r]));
    #pragma unroll
    for (int off = 1; off < 16; off <<= 1)
      mx = fmaxf(mx, __shfl_xor(mx, off, 64));
    float mo = mr[r];
    float mn = fmaxf(mo, mx);
    mr[r] = mn;
    float alpha = __expf(mo - mn);
    float ps = 0.f;
    #pragma unroll
    for (int ni = 0; ni < 4; ni++){
      float pp = __expf(sc[ni][r] - mn);
      sc[ni][r] = pp;
      ps += pp;
    }
    #pragma unroll
    for (int off = 1; off < 16; off <<= 1)
      ps += __shfl_xor(ps, off, 64);
    ls[r] = ls[r]*alpha + ps;
    #pragma unroll
    for (int ei = 0; ei < 4; ei++) oa[ei][r] *= alpha;   // component r only
  }
}

__device__ __forceinline__ void pv_accum(const f32x4* sc, const bf16x8 (*vf)[4], f32x4* oa,
                                         char* Pw, int lg, int lr){
  #pragma unroll
  for (int ni = 0; ni < 4; ni++)
    #pragma unroll
    for (int r = 0; r < 4; r++){
      int prow = lg*4 + r;
      int pcb = (ni*16 + lr)*2;
      *(unsigned short*)(Pw + prow*128 + (pcb ^ ((prow & 7) << 4))) = f2bf(sc[ni][r]);
    }
  #pragma unroll
  for (int kk = 0; kk < 2; kk++){
    bf16x8 pf = *(const bf16x8*)(Pw + lr*128 + ((kk*64 + lg*16) ^ ((lr & 7) << 4)));
    #pragma unroll
    for (int ei = 0; ei < 4; ei++)
      oa[ei] = __builtin_amdgcn_mfma_f32_16x16x32_bf16(pf, vf[kk][ei], oa[ei], 0, 0, 0);
  }
}

// ---------------- attn v3: paired q-tiles, shared K/V regs, K prefetch ----------------
// grid 512: bh = bid&31 (bh%8 pins XCD), p = bid>>5 in 0..15 -> q-tiles (p, 31-p).
// Wave w: rows [p*64+w*16, +16) and [(31-p)*64+w*16, +16). Constant 33 tiles/block causal.
__global__ __launch_bounds__(256, 2) void attn_fwd3(const unsigned short* __restrict__ qh,
                                                    const unsigned short* __restrict__ kh,
                                                    const unsigned short* __restrict__ vt,
                                                    unsigned short* __restrict__ cc,
                                                    const int* __restrict__ maskp){
  __shared__ __align__(16) unsigned short Ps[4][16*64]; // per-wave P, swizzled
  int tid = threadIdx.x, lane = tid & 63, w = tid >> 6;
  int lg = lane >> 4, lr = lane & 15;
  int bid = blockIdx.x;
  int bh = bid & 31;
  int p  = bid >> 5;                 // 0..15
  int causal = *maskp;
  int qtL = p, qtH = 31 - p;
  int wq0L = qtL*64 + w*16, wq0H = qtH*64 + w*16;
  const char* Q  = (const char*)(qh + (size_t)bh*131072);
  const char* K  = (const char*)(kh + (size_t)bh*131072);
  const char* VT = (const char*)(vt + (size_t)bh*131072);
  char* Pw = (char*)Ps[w];

  bf16x8 qfL[2], qfH[2];
  #pragma unroll
  for (int kk = 0; kk < 2; kk++){
    qfL[kk] = *(const bf16x8*)(Q + (size_t)(wq0L + lr)*128 + kk*64 + lg*16);
    qfH[kk] = *(const bf16x8*)(Q + (size_t)(wq0H + lr)*128 + kk*64 + lg*16);
  }

  f32x4 zf = {0.f,0.f,0.f,0.f};
  f32x4 oaL[4], oaH[4];
  float mrL[4], lsL[4], mrH[4], lsH[4];
  #pragma unroll
  for (int ei = 0; ei < 4; ei++){ oaL[ei] = zf; oaH[ei] = zf; }
  #pragma unroll
  for (int r = 0; r < 4; r++){ mrL[r] = -1e30f; lsL[r] = 0.f; mrH[r] = -1e30f; lsH[r] = 0.f; }

  int ntL = causal ? qtL + 1 : 32;
  int ntH = causal ? qtH + 1 : 32;   // ntH >= ntL always

  bf16x8 kc[2][4], kn[2][4], vf[2][4];
  #pragma unroll
  for (int kk = 0; kk < 2; kk++)
    #pragma unroll
    for (int ni = 0; ni < 4; ni++)
      kc[kk][ni] = *(const bf16x8*)(K + (size_t)(ni*16 + lr)*128 + kk*64 + lg*16);

  for (int t = 0; t < ntH; t++){
    // V(t) issue (used ~600 cyc later, after both QK+softmax)
    #pragma unroll
    for (int kk = 0; kk < 2; kk++)
      #pragma unroll
      for (int ei = 0; ei < 4; ei++)
        vf[kk][ei] = *(const bf16x8*)(VT + (size_t)(ei*16 + lr)*4096 + t*128 + kk*64 + lg*16);
    // K(t+1) prefetch
    if (t + 1 < ntH){
      #pragma unroll
      for (int kk = 0; kk < 2; kk++)
        #pragma unroll
        for (int ni = 0; ni < 4; ni++)
          kn[kk][ni] = *(const bf16x8*)(K + (size_t)((t+1)*64 + ni*16 + lr)*128 + kk*64 + lg*16);
    }

    bool doL = t < ntL;                        // block-uniform
    f32x4 scL[4], scH[4];
    #pragma unroll
    for (int ni = 0; ni < 4; ni++){ scL[ni] = zf; scH[ni] = zf; }

    // QK for both chains off one K set (32 MFMA per load-set during overlap)
    #pragma unroll
    for (int kk = 0; kk < 2; kk++)
      #pragma unroll
      for (int ni = 0; ni < 4; ni++){
        if (doL) scL[ni] = __builtin_amdgcn_mfma_f32_16x16x32_bf16(qfL[kk], kc[kk][ni], scL[ni], 0, 0, 0);
        scH[ni] = __builtin_amdgcn_mfma_f32_16x16x32_bf16(qfH[kk], kc[kk][ni], scH[ni], 0, 0, 0);
      }

    if (causal && doL && t == qtL){
      #pragma unroll
      for (int ni = 0; ni < 4; ni++)
        #pragma unroll
        for (int r = 0; r < 4; r++){
          int qrow = wq0L + lg*4 + r;
          int kvc  = t*64 + ni*16 + lr;
          if (kvc > qrow) scL[ni][r] = -1e9f;
        }
    }
    if (causal && t == qtH){
      #pragma unroll
      for (int ni = 0; ni < 4; ni++)
        #pragma unroll
        for (int r = 0; r < 4; r++){
          int qrow = wq0H + lg*4 + r;
          int kvc  = t*64 + ni*16 + lr;
          if (kvc > qrow) scH[ni][r] = -1e9f;
        }
    }

    if (doL) online_sm(scL, mrL, lsL, oaL);
    online_sm(scH, mrH, lsH, oaH);

    if (doL) pv_accum(scL, vf, oaL, Pw, lg, lr);   // in-order DS: reuse Pw for both
    pv_accum(scH, vf, oaH, Pw, lg, lr);

    #pragma unroll
    for (int kk = 0; kk < 2; kk++)
      #pragma unroll
      for (int ni = 0; ni < 4; ni++)
        kc[kk][ni] = kn[kk][ni];
  }

  // writeout: concat[b][q][h*64+e] bf16, both tiles
  int b = bh >> 4, h = bh & 15;
  #pragma unroll
  for (int r = 0; r < 4; r++){
    float invL = 1.f / lsL[r];
    float invH = 1.f / lsH[r];
    int qL = wq0L + lg*4 + r;
    int qH = wq0H + lg*4 + r;
    size_t rbL = (size_t)(b*2048 + qL)*1024 + h*64;
    size_t rbH = (size_t)(b*2048 + qH)*1024 + h*64;
    #pragma unroll
    for (int ei = 0; ei < 4; ei++){
      int e = ei*16 + lr;
      cc[rbL + e] = f2bf(oaL[ei][r] * invL);
      cc[rbH + e] = f2bf(oaH[ei][r] * invH);
    }
  }
}

// ---------------- launch ----------------
extern "C" void kernel_launch(void* const* d_in, const int* in_sizes, int n_in,
                              void* d_out, int out_size, void* d_ws, size_t ws_size,
                              hipStream_t stream){
  const float* query = (const float*)d_in[0];
  const float* key_i = (const float*)d_in[1];
  const float* value = (const float*)d_in[2];
  const float* Wq = (const float*)d_in[3];
  const float* bq = (const float*)d_in[4];
  const float* Wk = (const float*)d_in[5];
  const float* bk = (const float*)d_in[6];
  const float* Wv = (const float*)d_in[7];
  const float* bv = (const float*)d_in[8];
  const float* Wo = (const float*)d_in[9];
  const float* bo = (const float*)d_in[10];
  const int* mask = (const int*)d_in[11];

  char* ws = (char*)d_ws;
  const size_t ACT = 8388608;   // 4096*1024 bf16
  unsigned short* Xq  = (unsigned short*)(ws + 0*ACT);
  unsigned short* Xk  = (unsigned short*)(ws + 1*ACT);
  unsigned short* Xv  = (unsigned short*)(ws + 2*ACT);
  unsigned short* qh  = (unsigned short*)(ws + 3*ACT);  // [B,H,S,DH]
  unsigned short* kh  = (unsigned short*)(ws + 4*ACT);
  unsigned short* vh  = (unsigned short*)(ws + 5*ACT);
  unsigned short* cc  = (unsigned short*)(ws + 6*ACT);  // concat [B,S,D]
  unsigned short* WqT = (unsigned short*)(ws + 7*ACT);            // [1024][1024] bf16
  unsigned short* WkT = (unsigned short*)(ws + 7*ACT + 2097152);
  unsigned short* WvT = (unsigned short*)(ws + 7*ACT + 4194304);
  unsigned short* WoT = (unsigned short*)(ws + 7*ACT + 6291456);
  unsigned short* vtr = Xq;  // V^T [B,H,DH,S]; reuses Xq slot (dead after gemm_qkv)

  convert3<<<6144, 256, 0, stream>>>(query, key_i, value, Xq, Xk, Xv);

  transpose_bf16<<<dim3(16,1,16), 256, 0, stream>>>(Wq, WqT, 1024, 64, 65536, 65536);
  transpose_bf16<<<dim3(16,1,16), 256, 0, stream>>>(Wk, WkT, 1024, 64, 65536, 65536);
  transpose_bf16<<<dim3(16,1,16), 256, 0, stream>>>(Wv, WvT, 1024, 64, 65536, 65536);
  transpose_bf16<<<dim3(16,16,1), 256, 0, stream>>>(Wo, WoT, 1024, 1024, 0, 0);

  gemm_qkv<<<dim3(8,32,3), 256, 0, stream>>>(Xq, Xk, Xv, WqT, WkT, WvT, bq, bk, bv, qh, kh, vh);

  transpose_v<<<dim3(32,32), 256, 0, stream>>>(vh, vtr);

  attn_fwd3<<<512, 256, 0, stream>>>(qh, kh, vtr, cc, mask);

  gemm_out<<<dim3(8,32), 256, 0, stream>>>(cc, WoT, bo, (float*)d_out);
}